// Round 3
// baseline (1637.742 us; speedup 1.0000x reference)
//
#include <hip/hip_runtime.h>
#include <hip/hip_bf16.h>
#include <hip/hip_cooperative_groups.h>

namespace cg = cooperative_groups;

#define N_NODES 10000
#define N_EDGES 320000
#define HDIM    256
#define NCLS    40
#define WTOT    273448

typedef __attribute__((ext_vector_type(8))) short short8;
typedef __attribute__((ext_vector_type(4))) float floatx4;
typedef unsigned long long ull;
typedef unsigned short ushort;

__device__ __forceinline__ float bf2f(ushort u) {
    union { unsigned int i; float f; } v; v.i = ((unsigned int)u) << 16; return v.f;
}
__device__ __forceinline__ ushort f2bf(float f) {
    __hip_bfloat16 h = __float2bfloat16(f);
    return *reinterpret_cast<ushort*>(&h);
}

// ================= shared args =================

struct MegaArgs {
    const void* x;
    const void* ei;
    const void* wsrc[10];
    ushort* wdst[10];     // even: W_l, odd: b_l (bf16)
    int woffs[11];
    ushort* xb;
    int* src32;
    int* dst32;
    int* cnt;
    int* offs;
    int* woff;
    int* csr;
    float* dinv;
    ushort* tbuf;
    ushort* hbuf;
    float* t5;
    void* out;
};

// ================= phase helpers (used by mega kernel) =================

__device__ __forceinline__ void gemm256_phase(
        const ushort* __restrict__ A, const ushort* __restrict__ W,
        const float* __restrict__ dinv, ushort* __restrict__ T,
        int gw, int nwaves) {
    const int lane = threadIdx.x & 63;
    const int m = lane & 15;
    const int quad = lane >> 4;
    const int c0 = (gw & 15) * 16;

    short8 bfrag[8];
#pragma unroll
    for (int s = 0; s < 8; ++s)
#pragma unroll
        for (int j = 0; j < 8; ++j)
            bfrag[s][j] = (short)W[(size_t)(s * 32 + quad * 8 + j) * 256 + c0 + m];

    const int wst = nwaves >> 4;
    for (int rt = gw >> 4; rt < N_NODES / 16; rt += wst) {
        const int r0 = rt * 16;
        floatx4 acc = {0.f, 0.f, 0.f, 0.f};
        const ushort* arow = A + (size_t)(r0 + m) * 256 + quad * 8;
#pragma unroll
        for (int s = 0; s < 8; ++s) {
            short8 af = *(const short8*)(arow + s * 32);
            acc = __builtin_amdgcn_mfma_f32_16x16x32_bf16(af, bfrag[s], acc, 0, 0, 0);
        }
#pragma unroll
        for (int r = 0; r < 4; ++r) {
            int row = r0 + quad * 4 + r;
            float di = dinv[row];
            T[(size_t)row * 256 + c0 + m] = f2bf(acc[r] * di);
        }
    }
}

__device__ __forceinline__ void gemm40_phase(
        const ushort* __restrict__ A, const ushort* __restrict__ W,
        const float* __restrict__ dinv, float* __restrict__ T,
        int gw, int nwaves) {
    const int lane = threadIdx.x & 63;
    const int m = lane & 15;
    const int quad = lane >> 4;

    for (int u = gw; u < 3 * (N_NODES / 16); u += nwaves) {
        int cb = u / (N_NODES / 16);
        int rt = u - cb * (N_NODES / 16);
        int col = cb * 16 + m;
        bool colok = col < NCLS;

        short8 bfrag[8];
#pragma unroll
        for (int s = 0; s < 8; ++s)
#pragma unroll
            for (int j = 0; j < 8; ++j)
                bfrag[s][j] = colok ? (short)W[(size_t)(s * 32 + quad * 8 + j) * NCLS + col] : (short)0;

        const int r0 = rt * 16;
        floatx4 acc = {0.f, 0.f, 0.f, 0.f};
        const ushort* arow = A + (size_t)(r0 + m) * 256 + quad * 8;
#pragma unroll
        for (int s = 0; s < 8; ++s) {
            short8 af = *(const short8*)(arow + s * 32);
            acc = __builtin_amdgcn_mfma_f32_16x16x32_bf16(af, bfrag[s], acc, 0, 0, 0);
        }
        if (colok) {
#pragma unroll
            for (int r = 0; r < 4; ++r) {
                int row = r0 + quad * 4 + r;
                T[(size_t)row * NCLS + col] = acc[r] * dinv[row];
            }
        }
    }
}

__device__ __forceinline__ void accum16(float* acc, int4 r) {
    int d[4] = {r.x, r.y, r.z, r.w};
#pragma unroll
    for (int k = 0; k < 4; ++k) {
        union { int i; float f; } lo, hi;
        lo.i = d[k] << 16;
        hi.i = d[k] & 0xffff0000;
        acc[2 * k]     += lo.f;
        acc[2 * k + 1] += hi.f;
    }
}

__device__ __forceinline__ void agg256_phase(
        const ushort* __restrict__ T,
        const int* __restrict__ csr, const int* __restrict__ offs,
        const int* __restrict__ cnt, const float* __restrict__ dinv,
        const ushort* __restrict__ bias, ushort* __restrict__ H,
        int gw, int nwaves) {
    const int lane = threadIdx.x & 63;
    const int half = lane >> 5;
    const int q = lane & 31;

    for (int node = gw; node < N_NODES; node += nwaves) {
        const int start = offs[node];
        const int count = cnt[node];
        const float di = dinv[node];

        float acc[8];
        {
            int sinit = half ? N_NODES : node;
            int4 r = *(const int4*)(T + (size_t)sinit * 256 + q * 8);
#pragma unroll
            for (int k = 0; k < 4; ++k) {
                union { int i; float f; } lo, hi;
                int d = (&r.x)[k];
                lo.i = d << 16; hi.i = d & 0xffff0000;
                acc[2 * k] = lo.f; acc[2 * k + 1] = hi.f;
            }
        }

        for (int bj = 0; bj < count; bj += 64) {
            int mrem = count - bj;
            int mm = mrem < 64 ? mrem : 64;
            int idxv = (lane < mm) ? csr[start + bj + lane] : N_NODES;
            int j2 = 0;
            for (; j2 + 16 <= mm; j2 += 16) {
                int s0 = __shfl(idxv, j2 + 0  + half);
                int s1 = __shfl(idxv, j2 + 2  + half);
                int s2 = __shfl(idxv, j2 + 4  + half);
                int s3 = __shfl(idxv, j2 + 6  + half);
                int s4 = __shfl(idxv, j2 + 8  + half);
                int s5 = __shfl(idxv, j2 + 10 + half);
                int s6 = __shfl(idxv, j2 + 12 + half);
                int s7 = __shfl(idxv, j2 + 14 + half);
                int4 r0 = *(const int4*)(T + (size_t)s0 * 256 + q * 8);
                int4 r1 = *(const int4*)(T + (size_t)s1 * 256 + q * 8);
                int4 r2 = *(const int4*)(T + (size_t)s2 * 256 + q * 8);
                int4 r3 = *(const int4*)(T + (size_t)s3 * 256 + q * 8);
                int4 r4 = *(const int4*)(T + (size_t)s4 * 256 + q * 8);
                int4 r5 = *(const int4*)(T + (size_t)s5 * 256 + q * 8);
                int4 r6 = *(const int4*)(T + (size_t)s6 * 256 + q * 8);
                int4 r7 = *(const int4*)(T + (size_t)s7 * 256 + q * 8);
                accum16(acc, r0); accum16(acc, r1); accum16(acc, r2); accum16(acc, r3);
                accum16(acc, r4); accum16(acc, r5); accum16(acc, r6); accum16(acc, r7);
            }
            for (; j2 + 8 <= mm; j2 += 8) {
                int s0 = __shfl(idxv, j2 + half);
                int s1 = __shfl(idxv, j2 + 2 + half);
                int s2 = __shfl(idxv, j2 + 4 + half);
                int s3 = __shfl(idxv, j2 + 6 + half);
                int4 r0 = *(const int4*)(T + (size_t)s0 * 256 + q * 8);
                int4 r1 = *(const int4*)(T + (size_t)s1 * 256 + q * 8);
                int4 r2 = *(const int4*)(T + (size_t)s2 * 256 + q * 8);
                int4 r3 = *(const int4*)(T + (size_t)s3 * 256 + q * 8);
                accum16(acc, r0); accum16(acc, r1); accum16(acc, r2); accum16(acc, r3);
            }
            for (; j2 < mm; j2 += 2) {
                int s = __shfl(idxv, j2 + half);
                int4 r = *(const int4*)(T + (size_t)s * 256 + q * 8);
                accum16(acc, r);
            }
        }

#pragma unroll
        for (int i = 0; i < 8; ++i) acc[i] += __shfl_xor(acc[i], 32);

        if (half == 0) {
            int4 bv = *(const int4*)(bias + q * 8);
            int out_d[4];
#pragma unroll
            for (int k = 0; k < 4; ++k) {
                union { int i; float f; } lo, hi;
                int d = (&bv.x)[k];
                lo.i = d << 16; hi.i = d & 0xffff0000;
                float v0 = fmaxf(acc[2 * k] * di + lo.f, 0.f);
                float v1 = fmaxf(acc[2 * k + 1] * di + hi.f, 0.f);
                out_d[k] = (int)f2bf(v0) | ((int)f2bf(v1) << 16);
            }
            *(int4*)(H + (size_t)node * 256 + q * 8) = *(int4*)out_d;
        }
    }
}

__device__ __forceinline__ void aggsoft_phase(
        const float* __restrict__ T,
        const int* __restrict__ csr, const int* __restrict__ offs,
        const int* __restrict__ cnt, const float* __restrict__ dinv,
        const ushort* __restrict__ bias, void* __restrict__ out,
        int f32, int gw, int nwaves) {
    const int lane = threadIdx.x & 63;

    for (int node = gw; node < N_NODES; node += nwaves) {
        const int start = offs[node];
        const int count = cnt[node];
        const float di = dinv[node];

        float acc = (lane < NCLS) ? T[(size_t)node * NCLS + lane] : 0.f;
        for (int bj = 0; bj < count; bj += 64) {
            int mrem = count - bj;
            int mm = mrem < 64 ? mrem : 64;
            int idxv = (lane < mm) ? csr[start + bj + lane] : 0;
            int jj = 0;
            for (; jj + 8 <= mm; jj += 8) {
                int s0 = __shfl(idxv, jj + 0);
                int s1 = __shfl(idxv, jj + 1);
                int s2 = __shfl(idxv, jj + 2);
                int s3 = __shfl(idxv, jj + 3);
                int s4 = __shfl(idxv, jj + 4);
                int s5 = __shfl(idxv, jj + 5);
                int s6 = __shfl(idxv, jj + 6);
                int s7 = __shfl(idxv, jj + 7);
                if (lane < NCLS) {
                    float t0 = T[(size_t)s0 * NCLS + lane];
                    float t1 = T[(size_t)s1 * NCLS + lane];
                    float t2 = T[(size_t)s2 * NCLS + lane];
                    float t3 = T[(size_t)s3 * NCLS + lane];
                    float t4 = T[(size_t)s4 * NCLS + lane];
                    float t5v = T[(size_t)s5 * NCLS + lane];
                    float t6 = T[(size_t)s6 * NCLS + lane];
                    float t7 = T[(size_t)s7 * NCLS + lane];
                    acc += (t0 + t1) + (t2 + t3) + (t4 + t5v) + (t6 + t7);
                }
            }
            for (; jj < mm; ++jj) {
                int s = __shfl(idxv, jj);
                if (lane < NCLS) acc += T[(size_t)s * NCLS + lane];
            }
        }

        float l = (lane < NCLS) ? (acc * di + bf2f(bias[lane])) : -INFINITY;
        float mx = l;
#pragma unroll
        for (int o = 32; o > 0; o >>= 1) mx = fmaxf(mx, __shfl_xor(mx, o));
        float e = (lane < NCLS) ? __expf(l - mx) : 0.f;
        float sum = e;
#pragma unroll
        for (int o = 32; o > 0; o >>= 1) sum += __shfl_xor(sum, o);
        float ls = l - mx - __logf(sum);
        if (lane < NCLS) {
            size_t i0 = (size_t)node * NCLS + lane;
            size_t i1 = (size_t)N_NODES * NCLS + i0;
            if (f32) {
                ((float*)out)[i0] = ls;
                ((float*)out)[i1] = l;
            } else {
                ((ushort*)out)[i0] = f2bf(ls);
                ((ushort*)out)[i1] = f2bf(l);
            }
        }
    }
}

// ================= mega kernel (cooperative) =================

__global__ __launch_bounds__(256, 4)
void mega_kernel(MegaArgs a) {
    cg::grid_group grid = cg::this_grid();
    __shared__ int sflags[2];
    __shared__ int part[256];

    const int tid = threadIdx.x;
    const int gtid = blockIdx.x * 256 + tid;
    const int nthreads = gridDim.x * 256;
    const int gw = blockIdx.x * 4 + (tid >> 6);
    const int nwaves = gridDim.x * 4;

    // ---- P0: per-block dtype detection ----
    if (tid < 64) {
        const ushort* u = (const ushort*)a.x;
        int e = (u[2 * tid] >> 7) & 0xFF;
        ull badmask = __ballot(e < 100 || e > 140);
        const int* ii = (const int*)a.ei;
        ull oddnz = __ballot(ii[2 * tid + 1] != 0);
        if (tid == 0) {
            sflags[0] = (__popcll(badmask) >= 8) ? 1 : 0;
            sflags[1] = (oddnz == 0) ? 1 : 0;
        }
    }
    __syncthreads();
    const int f32 = sflags[0];
    const int ei64 = sflags[1];

    // ---- P1: conversions + edge decode + degree count (cnt pre-zeroed by memset) ----
    if (f32) {
        for (int i = gtid; i < N_NODES * HDIM / 4; i += nthreads) {
            float4 v = ((const float4*)a.x)[i];
            ull p = (ull)f2bf(v.x) | ((ull)f2bf(v.y) << 16) |
                    ((ull)f2bf(v.z) << 32) | ((ull)f2bf(v.w) << 48);
            ((ull*)a.xb)[i] = p;
        }
    } else {
        for (int i = gtid; i < N_NODES * HDIM / 4; i += nthreads)
            ((ull*)a.xb)[i] = ((const ull*)a.x)[i];
    }

    for (int i = gtid; i < WTOT; i += nthreads) {
        int t = 0;
#pragma unroll
        for (int k = 1; k < 10; ++k) t += (i >= a.woffs[k]);
        int local = i - a.woffs[t];
        ushort v;
        if (f32) v = f2bf(((const float*)a.wsrc[t])[local]);
        else     v = ((const ushort*)a.wsrc[t])[local];
        a.wdst[t][local] = v;
    }

    {
        const int* ii = (const int*)a.ei;
        for (int e = gtid; e < N_EDGES; e += nthreads) {
            int s, d;
            if (ei64) { s = ii[2 * e]; d = ii[2 * (N_EDGES + e)]; }
            else      { s = ii[e];     d = ii[N_EDGES + e]; }
            s = ((unsigned)s < N_NODES) ? s : 0;
            d = ((unsigned)d < N_NODES) ? d : 0;
            a.src32[e] = s;
            a.dst32[e] = d;
            atomicAdd(&a.cnt[d], 1);
        }
    }

    if (blockIdx.x == 0 && tid < 128) {
        if (tid < 64) ((ull*)(a.tbuf + (size_t)N_NODES * 256))[tid] = 0;
        else          ((ull*)(a.hbuf + (size_t)N_NODES * 256))[tid - 64] = 0;
    }
    __threadfence();
    grid.sync();

    // ---- P2: exclusive scan + dinv (block 0) ----
    if (blockIdx.x == 0) {
        const int CH = 40;
        int base = tid * CH;
        int s = 0;
        for (int j = 0; j < CH; ++j) {
            int i = base + j;
            if (i < N_NODES) s += a.cnt[i];
        }
        part[tid] = s;
        __syncthreads();
        for (int off = 1; off < 256; off <<= 1) {
            int v = (tid >= off) ? part[tid - off] : 0;
            __syncthreads();
            part[tid] += v;
            __syncthreads();
        }
        int run = (tid == 0) ? 0 : part[tid - 1];
        for (int j = 0; j < CH; ++j) {
            int i = base + j;
            if (i < N_NODES) {
                int c = a.cnt[i];
                a.offs[i] = run;
                a.woff[i] = run;
                a.dinv[i] = rsqrtf((float)c + 1.0f);
                run += c;
            }
        }
    }
    __threadfence();
    grid.sync();

    // ---- P3: CSR fill ----
    for (int e = gtid; e < N_EDGES; e += nthreads) {
        int d = a.dst32[e];
        int p = atomicAdd(&a.woff[d], 1);
        a.csr[p] = a.src32[e];
    }
    __threadfence();
    grid.sync();

    // ---- layers ----
    gemm256_phase(a.xb, a.wdst[0], a.dinv, a.tbuf, gw, nwaves);
    __threadfence();
    grid.sync();
    agg256_phase(a.tbuf, a.csr, a.offs, a.cnt, a.dinv, a.wdst[1], a.hbuf, gw, nwaves);
    __threadfence();
    grid.sync();
#pragma unroll 1
    for (int l = 1; l < 4; ++l) {
        gemm256_phase(a.hbuf, a.wdst[2 * l], a.dinv, a.tbuf, gw, nwaves);
        __threadfence();
        grid.sync();
        agg256_phase(a.tbuf, a.csr, a.offs, a.cnt, a.dinv, a.wdst[2 * l + 1], a.hbuf, gw, nwaves);
        __threadfence();
        grid.sync();
    }
    gemm40_phase(a.hbuf, a.wdst[8], a.dinv, a.t5, gw, nwaves);
    __threadfence();
    grid.sync();
    aggsoft_phase(a.t5, a.csr, a.offs, a.cnt, a.dinv, a.wdst[9], a.out, f32, gw, nwaves);
}

// ================= legacy pipeline (verified fallback) =================

__global__ void detect_kernel(const void* x, const void* ei, int* flags) {
    const int lane = threadIdx.x & 63;
    const ushort* u = (const ushort*)x;
    int e = (u[2 * lane] >> 7) & 0xFF;
    ull badmask = __ballot(e < 100 || e > 140);
    const int* ii = (const int*)ei;
    ull oddnz = __ballot(ii[2 * lane + 1] != 0);
    if (lane == 0) {
        flags[0] = (__popcll(badmask) >= 8) ? 1 : 0;
        flags[1] = (oddnz == 0) ? 1 : 0;
    }
}

struct PrepArgs {
    const void* x;
    const void* ei;
    const void* wsrc[10];
    ushort* wdst[10];
    int woffs[11];
    ushort* xb;
    int* src32;
    int* dst32;
    int* cnt;
    ushort* tbuf;
    ushort* hbuf;
    const int* flags;
};

#define PREP_XB 2500
#define PREP_WB 1069
#define PREP_EB 1250
#define PREP_ZB 40
#define PREP_SB 1
#define PREP_TOTAL (PREP_XB + PREP_WB + PREP_EB + PREP_ZB + PREP_SB)

__global__ __launch_bounds__(256)
void prep_kernel(PrepArgs a) {
    const int b = blockIdx.x;
    const int f32 = a.flags[0];
    if (b < PREP_XB) {
        int i4 = b * 256 + threadIdx.x;
        if (f32) {
            float4 v = ((const float4*)a.x)[i4];
            ull p = (ull)f2bf(v.x) | ((ull)f2bf(v.y) << 16) |
                    ((ull)f2bf(v.z) << 32) | ((ull)f2bf(v.w) << 48);
            ((ull*)a.xb)[i4] = p;
        } else {
            ((ull*)a.xb)[i4] = ((const ull*)a.x)[i4];
        }
    } else if (b < PREP_XB + PREP_WB) {
        int i = (b - PREP_XB) * 256 + threadIdx.x;
        if (i < WTOT) {
            int t = 0;
#pragma unroll
            for (int k = 1; k < 10; ++k) t += (i >= a.woffs[k]);
            int local = i - a.woffs[t];
            ushort v;
            if (f32) v = f2bf(((const float*)a.wsrc[t])[local]);
            else     v = ((const ushort*)a.wsrc[t])[local];
            a.wdst[t][local] = v;
        }
    } else if (b < PREP_XB + PREP_WB + PREP_EB) {
        int e = (b - PREP_XB - PREP_WB) * 256 + threadIdx.x;
        const int* ii = (const int*)a.ei;
        int s, d;
        if (a.flags[1]) { s = ii[2 * e]; d = ii[2 * (N_EDGES + e)]; }
        else            { s = ii[e];     d = ii[N_EDGES + e]; }
        a.src32[e] = ((unsigned)s < N_NODES) ? s : 0;
        a.dst32[e] = ((unsigned)d < N_NODES) ? d : 0;
    } else if (b < PREP_XB + PREP_WB + PREP_EB + PREP_ZB) {
        int i = (b - PREP_XB - PREP_WB - PREP_EB) * 256 + threadIdx.x;
        if (i < N_NODES) a.cnt[i] = 0;
    } else {
        int t = threadIdx.x;
        if (t < 64)       ((ull*)(a.tbuf + (size_t)N_NODES * 256))[t] = 0;
        else if (t < 128) ((ull*)(a.hbuf + (size_t)N_NODES * 256))[t - 64] = 0;
    }
}

__global__ void count_kernel(const int* __restrict__ dst, int* __restrict__ cnt) {
    int e = blockIdx.x * 256 + threadIdx.x;
    if (e < N_EDGES) atomicAdd(&cnt[dst[e]], 1);
}

__global__ __launch_bounds__(1024)
void scan_dinv_kernel(const int* __restrict__ cnt, int* __restrict__ offs,
                      int* __restrict__ woff, float* __restrict__ dinv) {
    __shared__ int part[1024];
    const int t = threadIdx.x;
    const int CH = (N_NODES + 1023) / 1024;
    const int base = t * CH;
    int s = 0;
    for (int j = 0; j < CH; ++j) {
        int i = base + j;
        if (i < N_NODES) s += cnt[i];
    }
    part[t] = s;
    __syncthreads();
    for (int off = 1; off < 1024; off <<= 1) {
        int v = 0;
        if (t >= off) v = part[t - off];
        __syncthreads();
        part[t] += v;
        __syncthreads();
    }
    int run = (t == 0) ? 0 : part[t - 1];
    for (int j = 0; j < CH; ++j) {
        int i = base + j;
        if (i < N_NODES) {
            int c = cnt[i];
            offs[i] = run;
            woff[i] = run;
            dinv[i] = rsqrtf((float)c + 1.0f);
            run += c;
        }
    }
}

__global__ void fill_kernel(const int* __restrict__ src, const int* __restrict__ dst,
                            int* __restrict__ woff, int* __restrict__ csr) {
    int e = blockIdx.x * 256 + threadIdx.x;
    if (e < N_EDGES) {
        int d = dst[e];
        int p = atomicAdd(&woff[d], 1);
        csr[p] = src[e];
    }
}

__global__ __launch_bounds__(256)
void gemm256_kernel(const ushort* __restrict__ A, const ushort* __restrict__ W,
                    const float* __restrict__ dinv, ushort* __restrict__ T) {
    const int lane = threadIdx.x & 63;
    const int wave = threadIdx.x >> 6;
    const int m = lane & 15;
    const int quad = lane >> 4;
    const int c0 = blockIdx.x * 32;

    short8 bfrag[2][8];
#pragma unroll
    for (int t = 0; t < 2; ++t)
#pragma unroll
        for (int s = 0; s < 8; ++s)
#pragma unroll
            for (int j = 0; j < 8; ++j)
                bfrag[t][s][j] = (short)W[(size_t)(s * 32 + quad * 8 + j) * 256 + c0 + t * 16 + m];

    const int step = gridDim.y * 4;
    for (int rt = blockIdx.y * 4 + wave; rt < N_NODES / 16; rt += step) {
        const int r0 = rt * 16;
        floatx4 acc0 = {0.f, 0.f, 0.f, 0.f};
        floatx4 acc1 = {0.f, 0.f, 0.f, 0.f};
        const ushort* arow = A + (size_t)(r0 + m) * 256 + quad * 8;
#pragma unroll
        for (int s = 0; s < 8; ++s) {
            short8 af = *(const short8*)(arow + s * 32);
            acc0 = __builtin_amdgcn_mfma_f32_16x16x32_bf16(af, bfrag[0][s], acc0, 0, 0, 0);
            acc1 = __builtin_amdgcn_mfma_f32_16x16x32_bf16(af, bfrag[1][s], acc1, 0, 0, 0);
        }
#pragma unroll
        for (int r = 0; r < 4; ++r) {
            int row = r0 + quad * 4 + r;
            float di = dinv[row];
            T[(size_t)row * 256 + c0 + m]      = f2bf(acc0[r] * di);
            T[(size_t)row * 256 + c0 + 16 + m] = f2bf(acc1[r] * di);
        }
    }
}

__global__ __launch_bounds__(256)
void gemm40_kernel(const ushort* __restrict__ A, const ushort* __restrict__ W,
                   const float* __restrict__ dinv, float* __restrict__ T) {
    const int lane = threadIdx.x & 63;
    const int wave = threadIdx.x >> 6;
    const int m = lane & 15;
    const int quad = lane >> 4;
    const int col = blockIdx.x * 16 + m;
    const bool colok = col < NCLS;

    short8 bfrag[8];
#pragma unroll
    for (int s = 0; s < 8; ++s)
#pragma unroll
        for (int j = 0; j < 8; ++j)
            bfrag[s][j] = colok ? (short)W[(size_t)(s * 32 + quad * 8 + j) * NCLS + col] : (short)0;

    const int step = gridDim.y * 4;
    for (int rt = blockIdx.y * 4 + wave; rt < N_NODES / 16; rt += step) {
        const int r0 = rt * 16;
        floatx4 acc = {0.f, 0.f, 0.f, 0.f};
        const ushort* arow = A + (size_t)(r0 + m) * 256 + quad * 8;
#pragma unroll
        for (int s = 0; s < 8; ++s) {
            short8 af = *(const short8*)(arow + s * 32);
            acc = __builtin_amdgcn_mfma_f32_16x16x32_bf16(af, bfrag[s], acc, 0, 0, 0);
        }
        if (colok) {
#pragma unroll
            for (int r = 0; r < 4; ++r) {
                int row = r0 + quad * 4 + r;
                T[(size_t)row * NCLS + col] = acc[r] * dinv[row];
            }
        }
    }
}

__global__ __launch_bounds__(256)
void agg256_kernel(const ushort* __restrict__ T,
                   const int* __restrict__ csr, const int* __restrict__ offs,
                   const int* __restrict__ cnt, const float* __restrict__ dinv,
                   const ushort* __restrict__ bias,
                   ushort* __restrict__ H) {
    const int node = blockIdx.x * 4 + (threadIdx.x >> 6);
    agg256_phase(T, csr, offs, cnt, dinv, bias, H, node, N_NODES + 1);
}

__global__ __launch_bounds__(256)
void aggsoft_kernel(const float* __restrict__ T,
                    const int* __restrict__ csr, const int* __restrict__ offs,
                    const int* __restrict__ cnt, const float* __restrict__ dinv,
                    const ushort* __restrict__ bias,
                    void* __restrict__ out, const int* __restrict__ flags) {
    const int node = blockIdx.x * 4 + (threadIdx.x >> 6);
    aggsoft_phase(T, csr, offs, cnt, dinv, bias, out, flags[0], node, N_NODES + 1);
}

// ================= host =================

static inline size_t alup(size_t x) { return (x + 255) & ~(size_t)255; }

extern "C" void kernel_launch(void* const* d_in, const int* in_sizes, int n_in,
                              void* d_out, int out_size, void* d_ws, size_t ws_size,
                              hipStream_t stream) {
    char* w = (char*)d_ws;
    int* flags   = (int*)w;           w += alup(16);
    float* dinv  = (float*)w;         w += alup(N_NODES * 4);
    int* cnt     = (int*)w;           w += alup(N_NODES * 4);
    int* offs    = (int*)w;           w += alup(N_NODES * 4);
    int* woff    = (int*)w;           w += alup(N_NODES * 4);
    int* src32   = (int*)w;           w += alup(N_EDGES * 4);
    int* dst32   = (int*)w;           w += alup(N_EDGES * 4);
    int* csr     = (int*)w;           w += alup(N_EDGES * 4);
    ushort* xb   = (ushort*)w;        w += alup((size_t)N_NODES * HDIM * 2);
    ushort* wb[5]; ushort* bb[5];
    for (int l = 0; l < 5; ++l) {
        int wn = (l < 4) ? HDIM * HDIM : HDIM * NCLS;
        int bn = (l < 4) ? HDIM : NCLS;
        wb[l] = (ushort*)w; w += alup((size_t)wn * 2);
        bb[l] = (ushort*)w; w += alup((size_t)bn * 2);
    }
    ushort* tbuf = (ushort*)w;        w += alup((size_t)(N_NODES + 16) * HDIM * 2);
    ushort* hbuf = (ushort*)w;        w += alup((size_t)(N_NODES + 16) * HDIM * 2);
    float* t5    = (float*)w;         w += alup((size_t)N_NODES * NCLS * 4);

    int sizes[10] = { HDIM * HDIM, HDIM, HDIM * HDIM, HDIM, HDIM * HDIM, HDIM,
                      HDIM * HDIM, HDIM, HDIM * NCLS, NCLS };

    // ---- decide cooperative grid once (host-side queries only) ----
    static int coop_grid = -2;
    if (coop_grid == -2) {
        int dev = 0;
        hipGetDevice(&dev);
        hipDeviceProp_t props;
        hipError_t e1 = hipGetDeviceProperties(&props, dev);
        int maxPerCU = 0;
        hipError_t e2 = hipOccupancyMaxActiveBlocksPerMultiprocessor(
            &maxPerCU, mega_kernel, 256, 0);
        if (e1 != hipSuccess || e2 != hipSuccess || !props.cooperativeLaunch || maxPerCU < 1) {
            coop_grid = -1;
        } else {
            long g = (long)maxPerCU * (long)props.multiProcessorCount;
            if (g > 2048) g = 2048;
            g &= ~3L;                 // phases need nwaves % 16 == 0
            coop_grid = (g >= 16) ? (int)g : -1;
        }
    }

    bool coop_done = false;
    if (coop_grid > 0) {
        hipMemsetAsync(cnt, 0, N_NODES * 4, stream);

        MegaArgs ma;
        ma.x = d_in[0];
        ma.ei = d_in[1];
        int run = 0;
        for (int t = 0; t < 10; ++t) {
            ma.wsrc[t] = d_in[2 + t];
            ma.wdst[t] = (t & 1) ? bb[t >> 1] : wb[t >> 1];
            ma.woffs[t] = run;
            run += sizes[t];
        }
        ma.woffs[10] = run;
        ma.xb = xb; ma.src32 = src32; ma.dst32 = dst32;
        ma.cnt = cnt; ma.offs = offs; ma.woff = woff; ma.csr = csr;
        ma.dinv = dinv; ma.tbuf = tbuf; ma.hbuf = hbuf; ma.t5 = t5;
        ma.out = d_out;

        void* kargs[] = { &ma };
        hipError_t le = hipLaunchCooperativeKernel((void*)mega_kernel,
                                                   dim3(coop_grid), dim3(256),
                                                   kargs, 0, stream);
        if (le == hipSuccess) coop_done = true;
        else coop_grid = -1;   // don't retry on later calls
    }

    if (!coop_done) {
        // ---- legacy verified pipeline ----
        detect_kernel<<<1, 64, 0, stream>>>(d_in[0], d_in[1], flags);

        PrepArgs pa;
        pa.x = d_in[0];
        pa.ei = d_in[1];
        int run = 0;
        for (int t = 0; t < 10; ++t) {
            pa.wsrc[t] = d_in[2 + t];
            pa.wdst[t] = (t & 1) ? bb[t >> 1] : wb[t >> 1];
            pa.woffs[t] = run;
            run += sizes[t];
        }
        pa.woffs[10] = run;
        pa.xb = xb; pa.src32 = src32; pa.dst32 = dst32; pa.cnt = cnt;
        pa.tbuf = tbuf; pa.hbuf = hbuf; pa.flags = flags;

        prep_kernel<<<PREP_TOTAL, 256, 0, stream>>>(pa);

        const int eblk = (N_EDGES + 255) / 256;
        count_kernel<<<eblk, 256, 0, stream>>>(dst32, cnt);
        scan_dinv_kernel<<<1, 1024, 0, stream>>>(cnt, offs, woff, dinv);
        fill_kernel<<<eblk, 256, 0, stream>>>(src32, dst32, woff, csr);

        const int aggblk = N_NODES / 4;

        gemm256_kernel<<<dim3(8, 78), 256, 0, stream>>>(xb, wb[0], dinv, tbuf);
        agg256_kernel<<<aggblk, 256, 0, stream>>>(tbuf, csr, offs, cnt, dinv, bb[0], hbuf);
        for (int l = 1; l < 4; ++l) {
            gemm256_kernel<<<dim3(8, 78), 256, 0, stream>>>(hbuf, wb[l], dinv, tbuf);
            agg256_kernel<<<aggblk, 256, 0, stream>>>(tbuf, csr, offs, cnt, dinv, bb[l], hbuf);
        }
        gemm40_kernel<<<dim3(3, 80), 256, 0, stream>>>(hbuf, wb[4], dinv, t5);
        aggsoft_kernel<<<aggblk, 256, 0, stream>>>(t5, csr, offs, cnt, dinv, bb[4], d_out, flags);
    }
}

// Round 4
// 976.974 us; speedup vs baseline: 1.6763x; 1.6763x over previous
//
#include <hip/hip_runtime.h>
#include <hip/hip_bf16.h>
#include <hip/hip_cooperative_groups.h>

namespace cg = cooperative_groups;

#define N_NODES 10000
#define N_EDGES 320000
#define HDIM    256
#define NCLS    40
#define WTOT    273448

typedef __attribute__((ext_vector_type(8))) short short8;
typedef __attribute__((ext_vector_type(4))) float floatx4;
typedef unsigned long long ull;
typedef unsigned short ushort;

__device__ __forceinline__ float bf2f(ushort u) {
    union { unsigned int i; float f; } v; v.i = ((unsigned int)u) << 16; return v.f;
}
__device__ __forceinline__ ushort f2bf(float f) {
    __hip_bfloat16 h = __float2bfloat16(f);
    return *reinterpret_cast<ushort*>(&h);
}

// ================= shared args =================

struct MegaArgs {
    const void* x;
    const void* ei;
    const void* wsrc[10];
    ushort* wdst[10];     // even: W_l, odd: b_l (bf16)
    int woffs[11];
    ushort* xb;
    int* src32;
    int* dst32;
    int* cnt;
    int* offs;
    int* woff;
    int* csr;
    float* dinv;
    ushort* tbuf;
    ushort* hbuf;
    float* t5;
    void* out;
};

// ================= phase helpers =================

__device__ __forceinline__ void gemm256_phase(
        const ushort* __restrict__ A, const ushort* __restrict__ W,
        const float* __restrict__ dinv, ushort* __restrict__ T,
        int gw, int nwaves) {
    const int lane = threadIdx.x & 63;
    const int m = lane & 15;
    const int quad = lane >> 4;
    const int c0 = (gw & 15) * 16;

    short8 bfrag[8];
#pragma unroll
    for (int s = 0; s < 8; ++s)
#pragma unroll
        for (int j = 0; j < 8; ++j)
            bfrag[s][j] = (short)W[(size_t)(s * 32 + quad * 8 + j) * 256 + c0 + m];

    const int wst = nwaves >> 4;
    for (int rt = gw >> 4; rt < N_NODES / 16; rt += wst) {
        const int r0 = rt * 16;
        floatx4 acc = {0.f, 0.f, 0.f, 0.f};
        const ushort* arow = A + (size_t)(r0 + m) * 256 + quad * 8;
#pragma unroll
        for (int s = 0; s < 8; ++s) {
            short8 af = *(const short8*)(arow + s * 32);
            acc = __builtin_amdgcn_mfma_f32_16x16x32_bf16(af, bfrag[s], acc, 0, 0, 0);
        }
#pragma unroll
        for (int r = 0; r < 4; ++r) {
            int row = r0 + quad * 4 + r;
            float di = dinv[row];
            T[(size_t)row * 256 + c0 + m] = f2bf(acc[r] * di);
        }
    }
}

__device__ __forceinline__ void gemm40_phase(
        const ushort* __restrict__ A, const ushort* __restrict__ W,
        const float* __restrict__ dinv, float* __restrict__ T,
        int gw, int nwaves) {
    const int lane = threadIdx.x & 63;
    const int m = lane & 15;
    const int quad = lane >> 4;

    for (int u = gw; u < 3 * (N_NODES / 16); u += nwaves) {
        int cb = u / (N_NODES / 16);
        int rt = u - cb * (N_NODES / 16);
        int col = cb * 16 + m;
        bool colok = col < NCLS;

        short8 bfrag[8];
#pragma unroll
        for (int s = 0; s < 8; ++s)
#pragma unroll
            for (int j = 0; j < 8; ++j)
                bfrag[s][j] = colok ? (short)W[(size_t)(s * 32 + quad * 8 + j) * NCLS + col] : (short)0;

        const int r0 = rt * 16;
        floatx4 acc = {0.f, 0.f, 0.f, 0.f};
        const ushort* arow = A + (size_t)(r0 + m) * 256 + quad * 8;
#pragma unroll
        for (int s = 0; s < 8; ++s) {
            short8 af = *(const short8*)(arow + s * 32);
            acc = __builtin_amdgcn_mfma_f32_16x16x32_bf16(af, bfrag[s], acc, 0, 0, 0);
        }
        if (colok) {
#pragma unroll
            for (int r = 0; r < 4; ++r) {
                int row = r0 + quad * 4 + r;
                T[(size_t)row * NCLS + col] = acc[r] * dinv[row];
            }
        }
    }
}

__device__ __forceinline__ void accum16(float* acc, int4 r) {
    int d[4] = {r.x, r.y, r.z, r.w};
#pragma unroll
    for (int k = 0; k < 4; ++k) {
        union { int i; float f; } lo, hi;
        lo.i = d[k] << 16;
        hi.i = d[k] & 0xffff0000;
        acc[2 * k]     += lo.f;
        acc[2 * k + 1] += hi.f;
    }
}

__device__ __forceinline__ void agg256_phase(
        const ushort* __restrict__ T,
        const int* __restrict__ csr, const int* __restrict__ offs,
        const int* __restrict__ cnt, const float* __restrict__ dinv,
        const ushort* __restrict__ bias, ushort* __restrict__ H,
        int gw, int nwaves) {
    const int lane = threadIdx.x & 63;
    const int half = lane >> 5;
    const int q = lane & 31;

    for (int node = gw; node < N_NODES; node += nwaves) {
        const int start = offs[node];
        const int count = cnt[node];
        const float di = dinv[node];

        float acc[8];
        {
            int sinit = half ? N_NODES : node;
            int4 r = *(const int4*)(T + (size_t)sinit * 256 + q * 8);
#pragma unroll
            for (int k = 0; k < 4; ++k) {
                union { int i; float f; } lo, hi;
                int d = (&r.x)[k];
                lo.i = d << 16; hi.i = d & 0xffff0000;
                acc[2 * k] = lo.f; acc[2 * k + 1] = hi.f;
            }
        }

        for (int bj = 0; bj < count; bj += 64) {
            int mrem = count - bj;
            int mm = mrem < 64 ? mrem : 64;
            int idxv = (lane < mm) ? csr[start + bj + lane] : N_NODES;
            int j2 = 0;
            for (; j2 + 16 <= mm; j2 += 16) {
                int s0 = __shfl(idxv, j2 + 0  + half);
                int s1 = __shfl(idxv, j2 + 2  + half);
                int s2 = __shfl(idxv, j2 + 4  + half);
                int s3 = __shfl(idxv, j2 + 6  + half);
                int s4 = __shfl(idxv, j2 + 8  + half);
                int s5 = __shfl(idxv, j2 + 10 + half);
                int s6 = __shfl(idxv, j2 + 12 + half);
                int s7 = __shfl(idxv, j2 + 14 + half);
                int4 r0 = *(const int4*)(T + (size_t)s0 * 256 + q * 8);
                int4 r1 = *(const int4*)(T + (size_t)s1 * 256 + q * 8);
                int4 r2 = *(const int4*)(T + (size_t)s2 * 256 + q * 8);
                int4 r3 = *(const int4*)(T + (size_t)s3 * 256 + q * 8);
                int4 r4 = *(const int4*)(T + (size_t)s4 * 256 + q * 8);
                int4 r5 = *(const int4*)(T + (size_t)s5 * 256 + q * 8);
                int4 r6 = *(const int4*)(T + (size_t)s6 * 256 + q * 8);
                int4 r7 = *(const int4*)(T + (size_t)s7 * 256 + q * 8);
                accum16(acc, r0); accum16(acc, r1); accum16(acc, r2); accum16(acc, r3);
                accum16(acc, r4); accum16(acc, r5); accum16(acc, r6); accum16(acc, r7);
            }
            for (; j2 + 8 <= mm; j2 += 8) {
                int s0 = __shfl(idxv, j2 + half);
                int s1 = __shfl(idxv, j2 + 2 + half);
                int s2 = __shfl(idxv, j2 + 4 + half);
                int s3 = __shfl(idxv, j2 + 6 + half);
                int4 r0 = *(const int4*)(T + (size_t)s0 * 256 + q * 8);
                int4 r1 = *(const int4*)(T + (size_t)s1 * 256 + q * 8);
                int4 r2 = *(const int4*)(T + (size_t)s2 * 256 + q * 8);
                int4 r3 = *(const int4*)(T + (size_t)s3 * 256 + q * 8);
                accum16(acc, r0); accum16(acc, r1); accum16(acc, r2); accum16(acc, r3);
            }
            for (; j2 < mm; j2 += 2) {
                int s = __shfl(idxv, j2 + half);
                int4 r = *(const int4*)(T + (size_t)s * 256 + q * 8);
                accum16(acc, r);
            }
        }

#pragma unroll
        for (int i = 0; i < 8; ++i) acc[i] += __shfl_xor(acc[i], 32);

        if (half == 0) {
            int4 bv = *(const int4*)(bias + q * 8);
            int out_d[4];
#pragma unroll
            for (int k = 0; k < 4; ++k) {
                union { int i; float f; } lo, hi;
                int d = (&bv.x)[k];
                lo.i = d << 16; hi.i = d & 0xffff0000;
                float v0 = fmaxf(acc[2 * k] * di + lo.f, 0.f);
                float v1 = fmaxf(acc[2 * k + 1] * di + hi.f, 0.f);
                out_d[k] = (int)f2bf(v0) | ((int)f2bf(v1) << 16);
            }
            *(int4*)(H + (size_t)node * 256 + q * 8) = *(int4*)out_d;
        }
    }
}

__device__ __forceinline__ void aggsoft_phase(
        const float* __restrict__ T,
        const int* __restrict__ csr, const int* __restrict__ offs,
        const int* __restrict__ cnt, const float* __restrict__ dinv,
        const ushort* __restrict__ bias, void* __restrict__ out,
        int f32, int gw, int nwaves) {
    const int lane = threadIdx.x & 63;

    for (int node = gw; node < N_NODES; node += nwaves) {
        const int start = offs[node];
        const int count = cnt[node];
        const float di = dinv[node];

        float acc = (lane < NCLS) ? T[(size_t)node * NCLS + lane] : 0.f;
        for (int bj = 0; bj < count; bj += 64) {
            int mrem = count - bj;
            int mm = mrem < 64 ? mrem : 64;
            int idxv = (lane < mm) ? csr[start + bj + lane] : 0;
            int jj = 0;
            for (; jj + 8 <= mm; jj += 8) {
                int s0 = __shfl(idxv, jj + 0);
                int s1 = __shfl(idxv, jj + 1);
                int s2 = __shfl(idxv, jj + 2);
                int s3 = __shfl(idxv, jj + 3);
                int s4 = __shfl(idxv, jj + 4);
                int s5 = __shfl(idxv, jj + 5);
                int s6 = __shfl(idxv, jj + 6);
                int s7 = __shfl(idxv, jj + 7);
                if (lane < NCLS) {
                    float t0 = T[(size_t)s0 * NCLS + lane];
                    float t1 = T[(size_t)s1 * NCLS + lane];
                    float t2 = T[(size_t)s2 * NCLS + lane];
                    float t3 = T[(size_t)s3 * NCLS + lane];
                    float t4 = T[(size_t)s4 * NCLS + lane];
                    float t5v = T[(size_t)s5 * NCLS + lane];
                    float t6 = T[(size_t)s6 * NCLS + lane];
                    float t7 = T[(size_t)s7 * NCLS + lane];
                    acc += (t0 + t1) + (t2 + t3) + (t4 + t5v) + (t6 + t7);
                }
            }
            for (; jj < mm; ++jj) {
                int s = __shfl(idxv, jj);
                if (lane < NCLS) acc += T[(size_t)s * NCLS + lane];
            }
        }

        float l = (lane < NCLS) ? (acc * di + bf2f(bias[lane])) : -INFINITY;
        float mx = l;
#pragma unroll
        for (int o = 32; o > 0; o >>= 1) mx = fmaxf(mx, __shfl_xor(mx, o));
        float e = (lane < NCLS) ? __expf(l - mx) : 0.f;
        float sum = e;
#pragma unroll
        for (int o = 32; o > 0; o >>= 1) sum += __shfl_xor(sum, o);
        float ls = l - mx - __logf(sum);
        if (lane < NCLS) {
            size_t i0 = (size_t)node * NCLS + lane;
            size_t i1 = (size_t)N_NODES * NCLS + i0;
            if (f32) {
                ((float*)out)[i0] = ls;
                ((float*)out)[i1] = l;
            } else {
                ((ushort*)out)[i0] = f2bf(ls);
                ((ushort*)out)[i1] = f2bf(l);
            }
        }
    }
}

// ================= mega kernel v2 (cooperative, no explicit fences, 11 syncs) =================

__global__ __launch_bounds__(256, 4)
void mega_kernel(MegaArgs a) {
    cg::grid_group grid = cg::this_grid();
    __shared__ int sflags[2];
    __shared__ int part[256];

    const int tid = threadIdx.x;
    const int gtid = blockIdx.x * 256 + tid;
    const int nthreads = gridDim.x * 256;
    const int gw = blockIdx.x * 4 + (tid >> 6);
    const int nwaves = gridDim.x * 4;

    // ---- P0: per-block dtype detection ----
    if (tid < 64) {
        const ushort* u = (const ushort*)a.x;
        int e = (u[2 * tid] >> 7) & 0xFF;
        ull badmask = __ballot(e < 100 || e > 140);
        const int* ii = (const int*)a.ei;
        ull oddnz = __ballot(ii[2 * tid + 1] != 0);
        if (tid == 0) {
            sflags[0] = (__popcll(badmask) >= 8) ? 1 : 0;
            sflags[1] = (oddnz == 0) ? 1 : 0;
        }
    }
    __syncthreads();
    const int f32 = sflags[0];
    const int ei64 = sflags[1];

    // ---- P1: weight conversion + edge decode + degree count + sentinels ----
    for (int i = gtid; i < WTOT; i += nthreads) {
        int t = 0;
#pragma unroll
        for (int k = 1; k < 10; ++k) t += (i >= a.woffs[k]);
        int local = i - a.woffs[t];
        ushort v;
        if (f32) v = f2bf(((const float*)a.wsrc[t])[local]);
        else     v = ((const ushort*)a.wsrc[t])[local];
        a.wdst[t][local] = v;
    }
    {
        const int* ii = (const int*)a.ei;
        for (int e = gtid; e < N_EDGES; e += nthreads) {
            int s, d;
            if (ei64) { s = ii[2 * e]; d = ii[2 * (N_EDGES + e)]; }
            else      { s = ii[e];     d = ii[N_EDGES + e]; }
            s = ((unsigned)s < N_NODES) ? s : 0;
            d = ((unsigned)d < N_NODES) ? d : 0;
            a.src32[e] = s;
            a.dst32[e] = d;
            atomicAdd(&a.cnt[d], 1);
        }
    }
    if (blockIdx.x == 0 && tid < 128) {
        if (tid < 64) ((ull*)(a.tbuf + (size_t)N_NODES * 256))[tid] = 0;
        else          ((ull*)(a.hbuf + (size_t)N_NODES * 256))[tid - 64] = 0;
    }
    grid.sync();   // S1

    // ---- P2: block 0 scans degrees; all other blocks convert x ----
    if (blockIdx.x == 0) {
        const int CH = 40;
        int base = tid * CH;
        int s = 0;
        for (int j = 0; j < CH; ++j) {
            int i = base + j;
            if (i < N_NODES) s += a.cnt[i];
        }
        part[tid] = s;
        __syncthreads();
        for (int off = 1; off < 256; off <<= 1) {
            int v = (tid >= off) ? part[tid - off] : 0;
            __syncthreads();
            part[tid] += v;
            __syncthreads();
        }
        int run = (tid == 0) ? 0 : part[tid - 1];
        for (int j = 0; j < CH; ++j) {
            int i = base + j;
            if (i < N_NODES) {
                int c = a.cnt[i];
                a.offs[i] = run;
                a.woff[i] = run;
                a.dinv[i] = rsqrtf((float)c + 1.0f);
                run += c;
            }
        }
    } else {
        int g2 = (blockIdx.x - 1) * 256 + tid;
        int n2 = (gridDim.x - 1) * 256;
        if (f32) {
            for (int i = g2; i < N_NODES * HDIM / 4; i += n2) {
                float4 v = ((const float4*)a.x)[i];
                ull p = (ull)f2bf(v.x) | ((ull)f2bf(v.y) << 16) |
                        ((ull)f2bf(v.z) << 32) | ((ull)f2bf(v.w) << 48);
                ((ull*)a.xb)[i] = p;
            }
        } else {
            for (int i = g2; i < N_NODES * HDIM / 4; i += n2)
                ((ull*)a.xb)[i] = ((const ull*)a.x)[i];
        }
    }
    grid.sync();   // S2

    // ---- P3: CSR fill + GEMM layer 1 (disjoint data, one sync covers both) ----
    for (int e = gtid; e < N_EDGES; e += nthreads) {
        int d = a.dst32[e];
        int p = atomicAdd(&a.woff[d], 1);
        a.csr[p] = a.src32[e];
    }
    gemm256_phase(a.xb, a.wdst[0], a.dinv, a.tbuf, gw, nwaves);
    grid.sync();   // S3

    agg256_phase(a.tbuf, a.csr, a.offs, a.cnt, a.dinv, a.wdst[1], a.hbuf, gw, nwaves);
    grid.sync();   // S4
    gemm256_phase(a.hbuf, a.wdst[2], a.dinv, a.tbuf, gw, nwaves);
    grid.sync();   // S5
    agg256_phase(a.tbuf, a.csr, a.offs, a.cnt, a.dinv, a.wdst[3], a.hbuf, gw, nwaves);
    grid.sync();   // S6
    gemm256_phase(a.hbuf, a.wdst[4], a.dinv, a.tbuf, gw, nwaves);
    grid.sync();   // S7
    agg256_phase(a.tbuf, a.csr, a.offs, a.cnt, a.dinv, a.wdst[5], a.hbuf, gw, nwaves);
    grid.sync();   // S8
    gemm256_phase(a.hbuf, a.wdst[6], a.dinv, a.tbuf, gw, nwaves);
    grid.sync();   // S9
    agg256_phase(a.tbuf, a.csr, a.offs, a.cnt, a.dinv, a.wdst[7], a.hbuf, gw, nwaves);
    grid.sync();   // S10
    gemm40_phase(a.hbuf, a.wdst[8], a.dinv, a.t5, gw, nwaves);
    grid.sync();   // S11
    aggsoft_phase(a.t5, a.csr, a.offs, a.cnt, a.dinv, a.wdst[9], a.out, f32, gw, nwaves);
}

// ================= legacy pipeline (verified fallback) =================

__global__ void detect_kernel(const void* x, const void* ei, int* flags) {
    const int lane = threadIdx.x & 63;
    const ushort* u = (const ushort*)x;
    int e = (u[2 * lane] >> 7) & 0xFF;
    ull badmask = __ballot(e < 100 || e > 140);
    const int* ii = (const int*)ei;
    ull oddnz = __ballot(ii[2 * lane + 1] != 0);
    if (lane == 0) {
        flags[0] = (__popcll(badmask) >= 8) ? 1 : 0;
        flags[1] = (oddnz == 0) ? 1 : 0;
    }
}

struct PrepArgs {
    const void* x;
    const void* ei;
    const void* wsrc[10];
    ushort* wdst[10];
    int woffs[11];
    ushort* xb;
    int* src32;
    int* dst32;
    int* cnt;
    ushort* tbuf;
    ushort* hbuf;
    const int* flags;
};

#define PREP_XB 2500
#define PREP_WB 1069
#define PREP_EB 1250
#define PREP_ZB 40
#define PREP_SB 1
#define PREP_TOTAL (PREP_XB + PREP_WB + PREP_EB + PREP_ZB + PREP_SB)

__global__ __launch_bounds__(256)
void prep_kernel(PrepArgs a) {
    const int b = blockIdx.x;
    const int f32 = a.flags[0];
    if (b < PREP_XB) {
        int i4 = b * 256 + threadIdx.x;
        if (f32) {
            float4 v = ((const float4*)a.x)[i4];
            ull p = (ull)f2bf(v.x) | ((ull)f2bf(v.y) << 16) |
                    ((ull)f2bf(v.z) << 32) | ((ull)f2bf(v.w) << 48);
            ((ull*)a.xb)[i4] = p;
        } else {
            ((ull*)a.xb)[i4] = ((const ull*)a.x)[i4];
        }
    } else if (b < PREP_XB + PREP_WB) {
        int i = (b - PREP_XB) * 256 + threadIdx.x;
        if (i < WTOT) {
            int t = 0;
#pragma unroll
            for (int k = 1; k < 10; ++k) t += (i >= a.woffs[k]);
            int local = i - a.woffs[t];
            ushort v;
            if (f32) v = f2bf(((const float*)a.wsrc[t])[local]);
            else     v = ((const ushort*)a.wsrc[t])[local];
            a.wdst[t][local] = v;
        }
    } else if (b < PREP_XB + PREP_WB + PREP_EB) {
        int e = (b - PREP_XB - PREP_WB) * 256 + threadIdx.x;
        const int* ii = (const int*)a.ei;
        int s, d;
        if (a.flags[1]) { s = ii[2 * e]; d = ii[2 * (N_EDGES + e)]; }
        else            { s = ii[e];     d = ii[N_EDGES + e]; }
        a.src32[e] = ((unsigned)s < N_NODES) ? s : 0;
        a.dst32[e] = ((unsigned)d < N_NODES) ? d : 0;
    } else if (b < PREP_XB + PREP_WB + PREP_EB + PREP_ZB) {
        int i = (b - PREP_XB - PREP_WB - PREP_EB) * 256 + threadIdx.x;
        if (i < N_NODES) a.cnt[i] = 0;
    } else {
        int t = threadIdx.x;
        if (t < 64)       ((ull*)(a.tbuf + (size_t)N_NODES * 256))[t] = 0;
        else if (t < 128) ((ull*)(a.hbuf + (size_t)N_NODES * 256))[t - 64] = 0;
    }
}

__global__ void count_kernel(const int* __restrict__ dst, int* __restrict__ cnt) {
    int e = blockIdx.x * 256 + threadIdx.x;
    if (e < N_EDGES) atomicAdd(&cnt[dst[e]], 1);
}

__global__ __launch_bounds__(1024)
void scan_dinv_kernel(const int* __restrict__ cnt, int* __restrict__ offs,
                      int* __restrict__ woff, float* __restrict__ dinv) {
    __shared__ int part[1024];
    const int t = threadIdx.x;
    const int CH = (N_NODES + 1023) / 1024;
    const int base = t * CH;
    int s = 0;
    for (int j = 0; j < CH; ++j) {
        int i = base + j;
        if (i < N_NODES) s += cnt[i];
    }
    part[t] = s;
    __syncthreads();
    for (int off = 1; off < 1024; off <<= 1) {
        int v = 0;
        if (t >= off) v = part[t - off];
        __syncthreads();
        part[t] += v;
        __syncthreads();
    }
    int run = (t == 0) ? 0 : part[t - 1];
    for (int j = 0; j < CH; ++j) {
        int i = base + j;
        if (i < N_NODES) {
            int c = cnt[i];
            offs[i] = run;
            woff[i] = run;
            dinv[i] = rsqrtf((float)c + 1.0f);
            run += c;
        }
    }
}

__global__ void fill_kernel(const int* __restrict__ src, const int* __restrict__ dst,
                            int* __restrict__ woff, int* __restrict__ csr) {
    int e = blockIdx.x * 256 + threadIdx.x;
    if (e < N_EDGES) {
        int d = dst[e];
        int p = atomicAdd(&woff[d], 1);
        csr[p] = src[e];
    }
}

__global__ __launch_bounds__(256)
void gemm256_kernel(const ushort* __restrict__ A, const ushort* __restrict__ W,
                    const float* __restrict__ dinv, ushort* __restrict__ T) {
    const int lane = threadIdx.x & 63;
    const int wave = threadIdx.x >> 6;
    const int m = lane & 15;
    const int quad = lane >> 4;
    const int c0 = blockIdx.x * 32;

    short8 bfrag[2][8];
#pragma unroll
    for (int t = 0; t < 2; ++t)
#pragma unroll
        for (int s = 0; s < 8; ++s)
#pragma unroll
            for (int j = 0; j < 8; ++j)
                bfrag[t][s][j] = (short)W[(size_t)(s * 32 + quad * 8 + j) * 256 + c0 + t * 16 + m];

    const int step = gridDim.y * 4;
    for (int rt = blockIdx.y * 4 + wave; rt < N_NODES / 16; rt += step) {
        const int r0 = rt * 16;
        floatx4 acc0 = {0.f, 0.f, 0.f, 0.f};
        floatx4 acc1 = {0.f, 0.f, 0.f, 0.f};
        const ushort* arow = A + (size_t)(r0 + m) * 256 + quad * 8;
#pragma unroll
        for (int s = 0; s < 8; ++s) {
            short8 af = *(const short8*)(arow + s * 32);
            acc0 = __builtin_amdgcn_mfma_f32_16x16x32_bf16(af, bfrag[0][s], acc0, 0, 0, 0);
            acc1 = __builtin_amdgcn_mfma_f32_16x16x32_bf16(af, bfrag[1][s], acc1, 0, 0, 0);
        }
#pragma unroll
        for (int r = 0; r < 4; ++r) {
            int row = r0 + quad * 4 + r;
            float di = dinv[row];
            T[(size_t)row * 256 + c0 + m]      = f2bf(acc0[r] * di);
            T[(size_t)row * 256 + c0 + 16 + m] = f2bf(acc1[r] * di);
        }
    }
}

__global__ __launch_bounds__(256)
void gemm40_kernel(const ushort* __restrict__ A, const ushort* __restrict__ W,
                   const float* __restrict__ dinv, float* __restrict__ T) {
    const int lane = threadIdx.x & 63;
    const int wave = threadIdx.x >> 6;
    const int m = lane & 15;
    const int quad = lane >> 4;
    const int col = blockIdx.x * 16 + m;
    const bool colok = col < NCLS;

    short8 bfrag[8];
#pragma unroll
    for (int s = 0; s < 8; ++s)
#pragma unroll
        for (int j = 0; j < 8; ++j)
            bfrag[s][j] = colok ? (short)W[(size_t)(s * 32 + quad * 8 + j) * NCLS + col] : (short)0;

    const int step = gridDim.y * 4;
    for (int rt = blockIdx.y * 4 + wave; rt < N_NODES / 16; rt += step) {
        const int r0 = rt * 16;
        floatx4 acc = {0.f, 0.f, 0.f, 0.f};
        const ushort* arow = A + (size_t)(r0 + m) * 256 + quad * 8;
#pragma unroll
        for (int s = 0; s < 8; ++s) {
            short8 af = *(const short8*)(arow + s * 32);
            acc = __builtin_amdgcn_mfma_f32_16x16x32_bf16(af, bfrag[s], acc, 0, 0, 0);
        }
        if (colok) {
#pragma unroll
            for (int r = 0; r < 4; ++r) {
                int row = r0 + quad * 4 + r;
                T[(size_t)row * NCLS + col] = acc[r] * dinv[row];
            }
        }
    }
}

__global__ __launch_bounds__(256)
void agg256_kernel(const ushort* __restrict__ T,
                   const int* __restrict__ csr, const int* __restrict__ offs,
                   const int* __restrict__ cnt, const float* __restrict__ dinv,
                   const ushort* __restrict__ bias,
                   ushort* __restrict__ H) {
    const int node = blockIdx.x * 4 + (threadIdx.x >> 6);
    agg256_phase(T, csr, offs, cnt, dinv, bias, H, node, N_NODES + 1);
}

__global__ __launch_bounds__(256)
void aggsoft_kernel(const float* __restrict__ T,
                    const int* __restrict__ csr, const int* __restrict__ offs,
                    const int* __restrict__ cnt, const float* __restrict__ dinv,
                    const ushort* __restrict__ bias,
                    void* __restrict__ out, const int* __restrict__ flags) {
    const int node = blockIdx.x * 4 + (threadIdx.x >> 6);
    aggsoft_phase(T, csr, offs, cnt, dinv, bias, out, flags[0], node, N_NODES + 1);
}

// ================= host =================

static inline size_t alup(size_t x) { return (x + 255) & ~(size_t)255; }

extern "C" void kernel_launch(void* const* d_in, const int* in_sizes, int n_in,
                              void* d_out, int out_size, void* d_ws, size_t ws_size,
                              hipStream_t stream) {
    char* w = (char*)d_ws;
    int* flags   = (int*)w;           w += alup(16);
    float* dinv  = (float*)w;         w += alup(N_NODES * 4);
    int* cnt     = (int*)w;           w += alup(N_NODES * 4);
    int* offs    = (int*)w;           w += alup(N_NODES * 4);
    int* woff    = (int*)w;           w += alup(N_NODES * 4);
    int* src32   = (int*)w;           w += alup(N_EDGES * 4);
    int* dst32   = (int*)w;           w += alup(N_EDGES * 4);
    int* csr     = (int*)w;           w += alup(N_EDGES * 4);
    ushort* xb   = (ushort*)w;        w += alup((size_t)N_NODES * HDIM * 2);
    ushort* wb[5]; ushort* bb[5];
    for (int l = 0; l < 5; ++l) {
        int wn = (l < 4) ? HDIM * HDIM : HDIM * NCLS;
        int bn = (l < 4) ? HDIM : NCLS;
        wb[l] = (ushort*)w; w += alup((size_t)wn * 2);
        bb[l] = (ushort*)w; w += alup((size_t)bn * 2);
    }
    ushort* tbuf = (ushort*)w;        w += alup((size_t)(N_NODES + 16) * HDIM * 2);
    ushort* hbuf = (ushort*)w;        w += alup((size_t)(N_NODES + 16) * HDIM * 2);
    float* t5    = (float*)w;         w += alup((size_t)N_NODES * NCLS * 4);

    int sizes[10] = { HDIM * HDIM, HDIM, HDIM * HDIM, HDIM, HDIM * HDIM, HDIM,
                      HDIM * HDIM, HDIM, HDIM * NCLS, NCLS };

    // ---- decide cooperative grid once (host-side queries only) ----
    static int coop_grid = -2;
    if (coop_grid == -2) {
        int dev = 0;
        hipGetDevice(&dev);
        hipDeviceProp_t props;
        hipError_t e1 = hipGetDeviceProperties(&props, dev);
        int maxPerCU = 0;
        hipError_t e2 = hipOccupancyMaxActiveBlocksPerMultiprocessor(
            &maxPerCU, mega_kernel, 256, 0);
        if (e1 != hipSuccess || e2 != hipSuccess || !props.cooperativeLaunch || maxPerCU < 1) {
            coop_grid = -1;
        } else {
            long g = (long)maxPerCU * (long)props.multiProcessorCount;
            if (g > 1024) g = 1024;   // fewer blocks -> cheaper grid.sync; occupancy still ~50%
            g &= ~3L;                 // phases need nwaves % 16 == 0
            coop_grid = (g >= 16) ? (int)g : -1;
        }
    }

    bool coop_done = false;
    if (coop_grid > 0) {
        hipMemsetAsync(cnt, 0, N_NODES * 4, stream);

        MegaArgs ma;
        ma.x = d_in[0];
        ma.ei = d_in[1];
        int run = 0;
        for (int t = 0; t < 10; ++t) {
            ma.wsrc[t] = d_in[2 + t];
            ma.wdst[t] = (t & 1) ? bb[t >> 1] : wb[t >> 1];
            ma.woffs[t] = run;
            run += sizes[t];
        }
        ma.woffs[10] = run;
        ma.xb = xb; ma.src32 = src32; ma.dst32 = dst32;
        ma.cnt = cnt; ma.offs = offs; ma.woff = woff; ma.csr = csr;
        ma.dinv = dinv; ma.tbuf = tbuf; ma.hbuf = hbuf; ma.t5 = t5;
        ma.out = d_out;

        void* kargs[] = { &ma };
        hipError_t le = hipLaunchCooperativeKernel((void*)mega_kernel,
                                                   dim3(coop_grid), dim3(256),
                                                   kargs, 0, stream);
        if (le == hipSuccess) coop_done = true;
        else coop_grid = -1;   // don't retry on later calls
    }

    if (!coop_done) {
        // ---- legacy verified pipeline ----
        detect_kernel<<<1, 64, 0, stream>>>(d_in[0], d_in[1], flags);

        PrepArgs pa;
        pa.x = d_in[0];
        pa.ei = d_in[1];
        int run = 0;
        for (int t = 0; t < 10; ++t) {
            pa.wsrc[t] = d_in[2 + t];
            pa.wdst[t] = (t & 1) ? bb[t >> 1] : wb[t >> 1];
            pa.woffs[t] = run;
            run += sizes[t];
        }
        pa.woffs[10] = run;
        pa.xb = xb; pa.src32 = src32; pa.dst32 = dst32; pa.cnt = cnt;
        pa.tbuf = tbuf; pa.hbuf = hbuf; pa.flags = flags;

        prep_kernel<<<PREP_TOTAL, 256, 0, stream>>>(pa);

        const int eblk = (N_EDGES + 255) / 256;
        count_kernel<<<eblk, 256, 0, stream>>>(dst32, cnt);
        scan_dinv_kernel<<<1, 1024, 0, stream>>>(cnt, offs, woff, dinv);
        fill_kernel<<<eblk, 256, 0, stream>>>(src32, dst32, woff, csr);

        const int aggblk = N_NODES / 4;

        gemm256_kernel<<<dim3(8, 78), 256, 0, stream>>>(xb, wb[0], dinv, tbuf);
        agg256_kernel<<<aggblk, 256, 0, stream>>>(tbuf, csr, offs, cnt, dinv, bb[0], hbuf);
        for (int l = 1; l < 4; ++l) {
            gemm256_kernel<<<dim3(8, 78), 256, 0, stream>>>(hbuf, wb[l], dinv, tbuf);
            agg256_kernel<<<aggblk, 256, 0, stream>>>(tbuf, csr, offs, cnt, dinv, bb[l], hbuf);
        }
        gemm40_kernel<<<dim3(3, 80), 256, 0, stream>>>(hbuf, wb[4], dinv, t5);
        aggsoft_kernel<<<aggblk, 256, 0, stream>>>(t5, csr, offs, cnt, dinv, bb[4], d_out, flags);
    }
}

// Round 5
// 269.128 us; speedup vs baseline: 6.0854x; 3.6302x over previous
//
#include <hip/hip_runtime.h>
#include <hip/hip_bf16.h>

#define N_NODES 10000
#define N_EDGES 320000
#define HDIM    256
#define NCLS    40
#define WTOT    273448

typedef __attribute__((ext_vector_type(8))) short short8;
typedef __attribute__((ext_vector_type(4))) float floatx4;
typedef unsigned long long ull;
typedef unsigned short ushort;

__device__ __forceinline__ float bf2f(ushort u) {
    union { unsigned int i; float f; } v; v.i = ((unsigned int)u) << 16; return v.f;
}
__device__ __forceinline__ ushort f2bf(float f) {
    __hip_bfloat16 h = __float2bfloat16(f);
    return *reinterpret_cast<ushort*>(&h);
}

// Per-block dtype detection: flags computed from first 64 elements.
// f32: x is fp32 (exponent distribution check); ei64: edge_index is int64.
__device__ __forceinline__ void detect_flags(const void* x, const void* ei,
                                             int* sflags) {
    const int tid = threadIdx.x;
    if (tid < 64) {
        const ushort* u = (const ushort*)x;
        int e = (u[2 * tid] >> 7) & 0xFF;
        ull badmask = __ballot(e < 100 || e > 140);
        const int* ii = (const int*)ei;
        ull oddnz = __ballot(ii[2 * tid + 1] != 0);
        if (tid == 0) {
            sflags[0] = (__popcll(badmask) >= 8) ? 1 : 0;
            sflags[1] = (oddnz == 0) ? 1 : 0;
        }
    }
    __syncthreads();
}

// ---------------- fused prep: detect + x/W convert + edge decode + count ----------------

struct PrepArgs {
    const void* x;
    const void* ei;
    const void* wsrc[10];
    ushort* wdst[10];
    int woffs[11];
    ushort* xb;
    int* src32;
    int* dst32;
    int* cnt;       // pre-zeroed by hipMemsetAsync
    ushort* tbuf;
    ushort* hbuf;
    int* flags;     // written by sentinel block for later kernels
};

#define PREP_XB 2500
#define PREP_WB 1069
#define PREP_EB 1250
#define PREP_TOTAL (PREP_XB + PREP_WB + PREP_EB + 1)

__global__ __launch_bounds__(256)
void prep_kernel(PrepArgs a) {
    __shared__ int sflags[2];
    detect_flags(a.x, a.ei, sflags);
    const int f32 = sflags[0];
    const int b = blockIdx.x;

    if (b < PREP_XB) {
        int i4 = b * 256 + threadIdx.x;   // 2500*256 == 640,000 == N*H/4 exactly
        if (f32) {
            float4 v = ((const float4*)a.x)[i4];
            ull p = (ull)f2bf(v.x) | ((ull)f2bf(v.y) << 16) |
                    ((ull)f2bf(v.z) << 32) | ((ull)f2bf(v.w) << 48);
            ((ull*)a.xb)[i4] = p;
        } else {
            ((ull*)a.xb)[i4] = ((const ull*)a.x)[i4];
        }
    } else if (b < PREP_XB + PREP_WB) {
        int i = (b - PREP_XB) * 256 + threadIdx.x;
        if (i < WTOT) {
            int t = 0;
#pragma unroll
            for (int k = 1; k < 10; ++k) t += (i >= a.woffs[k]);
            int local = i - a.woffs[t];
            ushort v;
            if (f32) v = f2bf(((const float*)a.wsrc[t])[local]);
            else     v = ((const ushort*)a.wsrc[t])[local];
            a.wdst[t][local] = v;
        }
    } else if (b < PREP_XB + PREP_WB + PREP_EB) {
        int e = (b - PREP_XB - PREP_WB) * 256 + threadIdx.x;  // 1250*256 == N_EDGES
        const int* ii = (const int*)a.ei;
        int s, d;
        if (sflags[1]) { s = ii[2 * e]; d = ii[2 * (N_EDGES + e)]; }
        else           { s = ii[e];     d = ii[N_EDGES + e]; }
        s = ((unsigned)s < N_NODES) ? s : 0;
        d = ((unsigned)d < N_NODES) ? d : 0;
        a.src32[e] = s;
        a.dst32[e] = d;
        atomicAdd(&a.cnt[d], 1);        // count fused (cnt pre-zeroed)
    } else {
        // sentinel rows (row N_NODES) of tbuf/hbuf + publish flags
        int t = threadIdx.x;
        if (t < 64)       ((ull*)(a.tbuf + (size_t)N_NODES * 256))[t] = 0;
        else if (t < 128) ((ull*)(a.hbuf + (size_t)N_NODES * 256))[t - 64] = 0;
        if (t == 0) { a.flags[0] = sflags[0]; a.flags[1] = sflags[1]; }
    }
}

// ---------------- scan + dinv (1 block) ----------------

__global__ __launch_bounds__(1024)
void scan_dinv_kernel(const int* __restrict__ cnt, int* __restrict__ offs,
                      int* __restrict__ woff, float* __restrict__ dinv) {
    __shared__ int part[1024];
    const int t = threadIdx.x;
    const int CH = (N_NODES + 1023) / 1024;  // 10
    const int base = t * CH;
    int s = 0;
    for (int j = 0; j < CH; ++j) {
        int i = base + j;
        if (i < N_NODES) s += cnt[i];
    }
    part[t] = s;
    __syncthreads();
    for (int off = 1; off < 1024; off <<= 1) {
        int v = 0;
        if (t >= off) v = part[t - off];
        __syncthreads();
        part[t] += v;
        __syncthreads();
    }
    int run = (t == 0) ? 0 : part[t - 1];
    for (int j = 0; j < CH; ++j) {
        int i = base + j;
        if (i < N_NODES) {
            int c = cnt[i];
            offs[i] = run;
            woff[i] = run;
            dinv[i] = rsqrtf((float)c + 1.0f);
            run += c;
        }
    }
}

// ---------------- fused CSR-fill + GEMM layer 1 ----------------
// Blocks 0..1249: scatter edges into CSR. Blocks 1250..1873: gemm256 layer 1.
// Independent data; both depend only on prep+scan.

#define FILL_BLKS 1250
#define GEMM1_YT  78
#define FG_TOTAL  (FILL_BLKS + 8 * GEMM1_YT)

__global__ __launch_bounds__(256)
void fillgemm_kernel(const int* __restrict__ src, const int* __restrict__ dst,
                     int* __restrict__ woff, int* __restrict__ csr,
                     const ushort* __restrict__ A, const ushort* __restrict__ W,
                     const float* __restrict__ dinv, ushort* __restrict__ T) {
    const int b = blockIdx.x;
    if (b < FILL_BLKS) {
        int e = b * 256 + threadIdx.x;   // exact
        int d = dst[e];
        int p = atomicAdd(&woff[d], 1);
        csr[p] = src[e];
        return;
    }
    const int g = b - FILL_BLKS;
    const int lane = threadIdx.x & 63;
    const int wave = threadIdx.x >> 6;
    const int m = lane & 15;
    const int quad = lane >> 4;
    const int c0 = (g & 7) * 32;
    const int by = g >> 3;

    short8 bfrag[2][8];
#pragma unroll
    for (int t = 0; t < 2; ++t)
#pragma unroll
        for (int s = 0; s < 8; ++s)
#pragma unroll
            for (int j = 0; j < 8; ++j)
                bfrag[t][s][j] = (short)W[(size_t)(s * 32 + quad * 8 + j) * 256 + c0 + t * 16 + m];

    const int step = GEMM1_YT * 4;
    for (int rt = by * 4 + wave; rt < N_NODES / 16; rt += step) {
        const int r0 = rt * 16;
        floatx4 acc0 = {0.f, 0.f, 0.f, 0.f};
        floatx4 acc1 = {0.f, 0.f, 0.f, 0.f};
        const ushort* arow = A + (size_t)(r0 + m) * 256 + quad * 8;
#pragma unroll
        for (int s = 0; s < 8; ++s) {
            short8 af = *(const short8*)(arow + s * 32);
            acc0 = __builtin_amdgcn_mfma_f32_16x16x32_bf16(af, bfrag[0][s], acc0, 0, 0, 0);
            acc1 = __builtin_amdgcn_mfma_f32_16x16x32_bf16(af, bfrag[1][s], acc1, 0, 0, 0);
        }
#pragma unroll
        for (int r = 0; r < 4; ++r) {
            int row = r0 + quad * 4 + r;
            float di = dinv[row];
            T[(size_t)row * 256 + c0 + m]      = f2bf(acc0[r] * di);
            T[(size_t)row * 256 + c0 + 16 + m] = f2bf(acc1[r] * di);
        }
    }
}

// ---------------- GEMM 256-wide (layers 2-4), grid (8, 78) ----------------

__global__ __launch_bounds__(256)
void gemm256_kernel(const ushort* __restrict__ A, const ushort* __restrict__ W,
                    const float* __restrict__ dinv, ushort* __restrict__ T) {
    const int lane = threadIdx.x & 63;
    const int wave = threadIdx.x >> 6;
    const int m = lane & 15;
    const int quad = lane >> 4;
    const int c0 = blockIdx.x * 32;

    short8 bfrag[2][8];
#pragma unroll
    for (int t = 0; t < 2; ++t)
#pragma unroll
        for (int s = 0; s < 8; ++s)
#pragma unroll
            for (int j = 0; j < 8; ++j)
                bfrag[t][s][j] = (short)W[(size_t)(s * 32 + quad * 8 + j) * 256 + c0 + t * 16 + m];

    const int step = gridDim.y * 4;
    for (int rt = blockIdx.y * 4 + wave; rt < N_NODES / 16; rt += step) {
        const int r0 = rt * 16;
        floatx4 acc0 = {0.f, 0.f, 0.f, 0.f};
        floatx4 acc1 = {0.f, 0.f, 0.f, 0.f};
        const ushort* arow = A + (size_t)(r0 + m) * 256 + quad * 8;
#pragma unroll
        for (int s = 0; s < 8; ++s) {
            short8 af = *(const short8*)(arow + s * 32);
            acc0 = __builtin_amdgcn_mfma_f32_16x16x32_bf16(af, bfrag[0][s], acc0, 0, 0, 0);
            acc1 = __builtin_amdgcn_mfma_f32_16x16x32_bf16(af, bfrag[1][s], acc1, 0, 0, 0);
        }
#pragma unroll
        for (int r = 0; r < 4; ++r) {
            int row = r0 + quad * 4 + r;
            float di = dinv[row];
            T[(size_t)row * 256 + c0 + m]      = f2bf(acc0[r] * di);
            T[(size_t)row * 256 + c0 + 16 + m] = f2bf(acc1[r] * di);
        }
    }
}

// ---------------- GEMM 40-wide -> fp32 t5, grid (3, 80) ----------------

__global__ __launch_bounds__(256)
void gemm40_kernel(const ushort* __restrict__ A, const ushort* __restrict__ W,
                   const float* __restrict__ dinv, float* __restrict__ T) {
    const int lane = threadIdx.x & 63;
    const int wave = threadIdx.x >> 6;
    const int m = lane & 15;
    const int quad = lane >> 4;
    const int col = blockIdx.x * 16 + m;
    const bool colok = col < NCLS;

    short8 bfrag[8];
#pragma unroll
    for (int s = 0; s < 8; ++s)
#pragma unroll
        for (int j = 0; j < 8; ++j)
            bfrag[s][j] = colok ? (short)W[(size_t)(s * 32 + quad * 8 + j) * NCLS + col] : (short)0;

    const int step = gridDim.y * 4;
    for (int rt = blockIdx.y * 4 + wave; rt < N_NODES / 16; rt += step) {
        const int r0 = rt * 16;
        floatx4 acc = {0.f, 0.f, 0.f, 0.f};
        const ushort* arow = A + (size_t)(r0 + m) * 256 + quad * 8;
#pragma unroll
        for (int s = 0; s < 8; ++s) {
            short8 af = *(const short8*)(arow + s * 32);
            acc = __builtin_amdgcn_mfma_f32_16x16x32_bf16(af, bfrag[s], acc, 0, 0, 0);
        }
        if (colok) {
#pragma unroll
            for (int r = 0; r < 4; ++r) {
                int row = r0 + quad * 4 + r;
                T[(size_t)row * NCLS + col] = acc[r] * dinv[row];
            }
        }
    }
}

// ---------------- Aggregation 256-wide ----------------

__device__ __forceinline__ void accum16(float* acc, int4 r) {
    int d[4] = {r.x, r.y, r.z, r.w};
#pragma unroll
    for (int k = 0; k < 4; ++k) {
        union { int i; float f; } lo, hi;
        lo.i = d[k] << 16;
        hi.i = d[k] & 0xffff0000;
        acc[2 * k]     += lo.f;
        acc[2 * k + 1] += hi.f;
    }
}

__global__ __launch_bounds__(256)
void agg256_kernel(const ushort* __restrict__ T,
                   const int* __restrict__ csr, const int* __restrict__ offs,
                   const int* __restrict__ cnt, const float* __restrict__ dinv,
                   const ushort* __restrict__ bias,
                   ushort* __restrict__ H) {
    const int node = blockIdx.x * 4 + (threadIdx.x >> 6);
    const int lane = threadIdx.x & 63;
    const int half = lane >> 5;
    const int q = lane & 31;
    const int start = offs[node];
    const int count = cnt[node];
    const float di = dinv[node];

    float acc[8];
    {
        int sinit = half ? N_NODES : node;
        int4 r = *(const int4*)(T + (size_t)sinit * 256 + q * 8);
#pragma unroll
        for (int k = 0; k < 4; ++k) {
            union { int i; float f; } lo, hi;
            int d = (&r.x)[k];
            lo.i = d << 16; hi.i = d & 0xffff0000;
            acc[2 * k] = lo.f; acc[2 * k + 1] = hi.f;
        }
    }

    for (int bj = 0; bj < count; bj += 64) {
        int mrem = count - bj;
        int mm = mrem < 64 ? mrem : 64;
        int idxv = (lane < mm) ? csr[start + bj + lane] : N_NODES;
        int j2 = 0;
        for (; j2 + 8 <= mm; j2 += 8) {
            int s0 = __shfl(idxv, j2 + half);
            int s1 = __shfl(idxv, j2 + 2 + half);
            int s2 = __shfl(idxv, j2 + 4 + half);
            int s3 = __shfl(idxv, j2 + 6 + half);
            int4 r0 = *(const int4*)(T + (size_t)s0 * 256 + q * 8);
            int4 r1 = *(const int4*)(T + (size_t)s1 * 256 + q * 8);
            int4 r2 = *(const int4*)(T + (size_t)s2 * 256 + q * 8);
            int4 r3 = *(const int4*)(T + (size_t)s3 * 256 + q * 8);
            accum16(acc, r0); accum16(acc, r1); accum16(acc, r2); accum16(acc, r3);
        }
        for (; j2 < mm; j2 += 2) {
            int s = __shfl(idxv, j2 + half);
            int4 r = *(const int4*)(T + (size_t)s * 256 + q * 8);
            accum16(acc, r);
        }
    }

#pragma unroll
    for (int i = 0; i < 8; ++i) acc[i] += __shfl_xor(acc[i], 32);

    if (half == 0) {
        int4 bv = *(const int4*)(bias + q * 8);
        int out_d[4];
#pragma unroll
        for (int k = 0; k < 4; ++k) {
            union { int i; float f; } lo, hi;
            int d = (&bv.x)[k];
            lo.i = d << 16; hi.i = d & 0xffff0000;
            float v0 = fmaxf(acc[2 * k] * di + lo.f, 0.f);
            float v1 = fmaxf(acc[2 * k + 1] * di + hi.f, 0.f);
            out_d[k] = (int)f2bf(v0) | ((int)f2bf(v1) << 16);
        }
        *(int4*)(H + (size_t)node * 256 + q * 8) = *(int4*)out_d;
    }
}

// ---------------- Aggregation 40-wide + log_softmax + output ----------------

__global__ __launch_bounds__(256)
void aggsoft_kernel(const float* __restrict__ T,
                    const int* __restrict__ csr, const int* __restrict__ offs,
                    const int* __restrict__ cnt, const float* __restrict__ dinv,
                    const ushort* __restrict__ bias,
                    void* __restrict__ out, const int* __restrict__ flags) {
    const int node = blockIdx.x * 4 + (threadIdx.x >> 6);
    const int lane = threadIdx.x & 63;
    const int start = offs[node];
    const int count = cnt[node];
    const float di = dinv[node];

    float acc = (lane < NCLS) ? T[(size_t)node * NCLS + lane] : 0.f;
    for (int bj = 0; bj < count; bj += 64) {
        int mrem = count - bj;
        int mm = mrem < 64 ? mrem : 64;
        int idxv = (lane < mm) ? csr[start + bj + lane] : 0;
        int jj = 0;
        for (; jj + 4 <= mm; jj += 4) {
            int s0 = __shfl(idxv, jj + 0);
            int s1 = __shfl(idxv, jj + 1);
            int s2 = __shfl(idxv, jj + 2);
            int s3 = __shfl(idxv, jj + 3);
            if (lane < NCLS) {
                float t0 = T[(size_t)s0 * NCLS + lane];
                float t1 = T[(size_t)s1 * NCLS + lane];
                float t2 = T[(size_t)s2 * NCLS + lane];
                float t3 = T[(size_t)s3 * NCLS + lane];
                acc += t0 + t1 + t2 + t3;
            }
        }
        for (; jj < mm; ++jj) {
            int s = __shfl(idxv, jj);
            if (lane < NCLS) acc += T[(size_t)s * NCLS + lane];
        }
    }

    float l = (lane < NCLS) ? (acc * di + bf2f(bias[lane])) : -INFINITY;
    float mx = l;
#pragma unroll
    for (int o = 32; o > 0; o >>= 1) mx = fmaxf(mx, __shfl_xor(mx, o));
    float e = (lane < NCLS) ? __expf(l - mx) : 0.f;
    float sum = e;
#pragma unroll
    for (int o = 32; o > 0; o >>= 1) sum += __shfl_xor(sum, o);
    float ls = l - mx - __logf(sum);
    if (lane < NCLS) {
        size_t i0 = (size_t)node * NCLS + lane;
        size_t i1 = (size_t)N_NODES * NCLS + i0;
        if (flags[0]) {
            ((float*)out)[i0] = ls;
            ((float*)out)[i1] = l;
        } else {
            ((ushort*)out)[i0] = f2bf(ls);
            ((ushort*)out)[i1] = f2bf(l);
        }
    }
}

// ---------------- host ----------------

static inline size_t alup(size_t x) { return (x + 255) & ~(size_t)255; }

extern "C" void kernel_launch(void* const* d_in, const int* in_sizes, int n_in,
                              void* d_out, int out_size, void* d_ws, size_t ws_size,
                              hipStream_t stream) {
    char* w = (char*)d_ws;
    int* flags   = (int*)w;           w += alup(16);
    float* dinv  = (float*)w;         w += alup(N_NODES * 4);
    int* cnt     = (int*)w;           w += alup(N_NODES * 4);
    int* offs    = (int*)w;           w += alup(N_NODES * 4);
    int* woff    = (int*)w;           w += alup(N_NODES * 4);
    int* src32   = (int*)w;           w += alup(N_EDGES * 4);
    int* dst32   = (int*)w;           w += alup(N_EDGES * 4);
    int* csr     = (int*)w;           w += alup(N_EDGES * 4);
    ushort* xb   = (ushort*)w;        w += alup((size_t)N_NODES * HDIM * 2);
    ushort* wb[5]; ushort* bb[5];
    for (int l = 0; l < 5; ++l) {
        int wn = (l < 4) ? HDIM * HDIM : HDIM * NCLS;
        int bn = (l < 4) ? HDIM : NCLS;
        wb[l] = (ushort*)w; w += alup((size_t)wn * 2);
        bb[l] = (ushort*)w; w += alup((size_t)bn * 2);
    }
    ushort* tbuf = (ushort*)w;        w += alup((size_t)(N_NODES + 16) * HDIM * 2);
    ushort* hbuf = (ushort*)w;        w += alup((size_t)(N_NODES + 16) * HDIM * 2);
    float* t5    = (float*)w;         w += alup((size_t)N_NODES * NCLS * 4);

    // degree counters must be zero before prep's fused count
    hipMemsetAsync(cnt, 0, N_NODES * 4, stream);

    PrepArgs pa;
    pa.x = d_in[0];
    pa.ei = d_in[1];
    int sizes[10] = { HDIM * HDIM, HDIM, HDIM * HDIM, HDIM, HDIM * HDIM, HDIM,
                      HDIM * HDIM, HDIM, HDIM * NCLS, NCLS };
    int run = 0;
    for (int t = 0; t < 10; ++t) {
        pa.wsrc[t] = d_in[2 + t];
        pa.wdst[t] = (t & 1) ? bb[t >> 1] : wb[t >> 1];
        pa.woffs[t] = run;
        run += sizes[t];
    }
    pa.woffs[10] = run;  // == WTOT
    pa.xb = xb; pa.src32 = src32; pa.dst32 = dst32; pa.cnt = cnt;
    pa.tbuf = tbuf; pa.hbuf = hbuf; pa.flags = flags;

    prep_kernel<<<PREP_TOTAL, 256, 0, stream>>>(pa);
    scan_dinv_kernel<<<1, 1024, 0, stream>>>(cnt, offs, woff, dinv);
    fillgemm_kernel<<<FG_TOTAL, 256, 0, stream>>>(src32, dst32, woff, csr,
                                                  xb, wb[0], dinv, tbuf);

    const int aggblk = N_NODES / 4;  // 2500

    agg256_kernel<<<aggblk, 256, 0, stream>>>(tbuf, csr, offs, cnt, dinv, bb[0], hbuf);
    for (int l = 1; l < 4; ++l) {
        gemm256_kernel<<<dim3(8, 78), 256, 0, stream>>>(hbuf, wb[l], dinv, tbuf);
        agg256_kernel<<<aggblk, 256, 0, stream>>>(tbuf, csr, offs, cnt, dinv, bb[l], hbuf);
    }
    gemm40_kernel<<<dim3(3, 80), 256, 0, stream>>>(hbuf, wb[4], dinv, t5);
    aggsoft_kernel<<<aggblk, 256, 0, stream>>>(t5, csr, offs, cnt, dinv, bb[4], d_out, flags);
}